// Round 8
// baseline (21560.318 us; speedup 1.0000x reference)
//
#include <hip/hip_runtime.h>
#include <stdint.h>

// ---------------- problem constants ----------------
#define TSTEPS 512
#define NB     256
#define DIN    85
#define DPAD   96
#define HID    512
#define ODIM   33
#define OPAD   48
#define TBROWS (TSTEPS*NB)
#define NBLK   128          // 16 strips x 8 parts
#define SROWS  16
#define NPART  8
#define LROW   520          // padded LDS row stride (u16)

typedef unsigned int u32;
typedef unsigned short u16;
typedef unsigned long long u64;
typedef __bf16 bf16x8 __attribute__((ext_vector_type(8)));
typedef float  f32x4  __attribute__((ext_vector_type(4)));

__device__ __forceinline__ u16 f2bf(float f) {
  u32 u = __float_as_uint(f);
  return (u16)((u + 0x7FFFu + ((u >> 16) & 1u)) >> 16);   // RNE
}
__device__ __forceinline__ float bf2f(u16 h) {
  return __uint_as_float(((u32)h) << 16);
}
__device__ __forceinline__ bf16x8 bc8(uint4 v) { return __builtin_bit_cast(bf16x8, v); }
__device__ __forceinline__ f32x4 mfma_bf16(bf16x8 a, bf16x8 b, f32x4 c) {
  return __builtin_amdgcn_mfma_f32_16x16x32_bf16(a, b, c, 0, 0, 0);
}
__device__ __forceinline__ float fsigmoid(float x) { return 1.0f / (1.0f + __expf(-x)); }
__device__ __forceinline__ float ftanh(float x)    { return 2.0f / (1.0f + __expf(-2.0f*x)) - 1.0f; }

// agent-scope (LLC-coherent) relaxed ops for cross-block mutable data
__device__ __forceinline__ void st_u32_llc(u32* p, u32 v) {
  __hip_atomic_store(p, v, __ATOMIC_RELAXED, __HIP_MEMORY_SCOPE_AGENT);
}
__device__ __forceinline__ u32 ld_u32_llc(const u32* p) {
  return __hip_atomic_load(p, __ATOMIC_RELAXED, __HIP_MEMORY_SCOPE_AGENT);
}
__device__ __forceinline__ u64 ld_u64_llc(const u64* p) {
  return __hip_atomic_load(p, __ATOMIC_RELAXED, __HIP_MEMORY_SCOPE_AGENT);
}

// ---------------- prep: bf16 weight conversions ----------------
__global__ void __launch_bounds__(256) prep_kernel(
    const float* __restrict__ Whr, const float* __restrict__ Whz, const float* __restrict__ Whh,
    const float* __restrict__ Wxr, const float* __restrict__ Wxz, const float* __restrict__ Wxh,
    const float* __restrict__ Wro,
    u16* __restrict__ w_hb, u16* __restrict__ wx_hi, u16* __restrict__ wx_lo,
    u16* __restrict__ w_rob)
{
  int tid = blockIdx.x * blockDim.x + threadIdx.x;
  int np  = gridDim.x * blockDim.x;
  for (int i = tid; i < 3 * HID * HID; i += np) {
    int m = i / (HID * HID), r = i % (HID * HID);
    const float* src = (m == 0) ? Whr : ((m == 1) ? Whz : Whh);
    w_hb[i] = f2bf(src[r]);
  }
  for (int i = tid; i < 3 * HID * DPAD; i += np) {
    int m = i / (HID * DPAD), r = i % (HID * DPAD);
    int row = r / DPAD, k = r % DPAD;
    const float* src = (m == 0) ? Wxr : ((m == 1) ? Wxz : Wxh);
    u16 hi = 0, lo = 0;
    if (k < DIN) {
      float v = src[row * DIN + k];
      hi = f2bf(v);
      lo = f2bf(v - bf2f(hi));
    }
    wx_hi[i] = hi; wx_lo[i] = lo;
  }
  for (int i = tid; i < OPAD * HID; i += np) {
    int row = i / HID, k = i % HID;
    w_rob[i] = (row < ODIM) ? f2bf(Wro[row * HID + k]) : (u16)0;
  }
}

// ---------------- persistent recurrence kernel (single exchange per step) ----------------
__global__ void __launch_bounds__(256, 1) recur_kernel(
    const float* __restrict__ x,  const float* __restrict__ nr,
    const float* __restrict__ nz, const float* __restrict__ nh,
    const float* __restrict__ bhr, const float* __restrict__ bhz, const float* __restrict__ bhh,
    const u16* __restrict__ wx_hi, const u16* __restrict__ wx_lo, const u16* __restrict__ w_hb,
    u32* __restrict__ h_pk, u32* __restrict__ flags,
    u16* __restrict__ hs_out,
    const float* __restrict__ Wro, const float* __restrict__ bro, float* __restrict__ out,
    int do_c)
{
  // sBig: h split planes, overwritten by g split planes mid-step; phase-C f32 scratch
  __shared__ __attribute__((aligned(16))) u16 sBig[2 * SROWS * LROW];   // 33280 B
  __shared__ __attribute__((aligned(16))) u16 sX[3][2][SROWS][104];     // 19968 B

  u16 (*sHh)[LROW] = (u16(*)[LROW])sBig;
  u16 (*sHl)[LROW] = (u16(*)[LROW])(sBig + SROWS * LROW);
  u16 (*sGh)[LROW] = sHh;
  u16 (*sGl)[LROW] = sHl;
  float* sC2 = (float*)sBig;

  const int bid  = blockIdx.x;
  const int tid  = threadIdx.x;
  const int lane = tid & 63;
  const int wave = tid >> 6;
  const int strip = bid >> 3;     // 0..15
  const int part  = bid & 7;      // 0..7

  u32* gflag = flags + strip * 16;      // one 64B line per strip-group

  const int rowl = lane & 15;
  // R-full: this wave covers cols [wave*128, wave*128+128)
  int colR[8];
  #pragma unroll
  for (int nf = 0; nf < 8; ++nf) colR[nf] = wave * 128 + nf * 16 + rowl;
  // Z / Hhat slice: this block covers cols [part*64, part*64+64), this wave 16 of them
  const int colS = part * 64 + wave * 16 + rowl;

  const u16* WR = w_hb;
  const u16* WZ = w_hb + (size_t)HID * HID;
  const u16* WH = w_hb + (size_t)2 * HID * HID;
  const u16* WXRh = wx_hi;                                const u16* WXRl = wx_lo;
  const u16* WXZh = wx_hi + (size_t)HID * DPAD;           const u16* WXZl = wx_lo + (size_t)HID * DPAD;
  const u16* WXHh = wx_hi + (size_t)2 * HID * DPAD;       const u16* WXHl = wx_lo + (size_t)2 * HID * DPAD;

  float bR[8];
  #pragma unroll
  for (int nf = 0; nf < 8; ++nf) bR[nf] = bhr[colR[nf]];
  const float bZv = bhz[colS];
  const float bHv = bhh[colS];

  float h_old[4] = {0.f, 0.f, 0.f, 0.f};

  // zero all x buffers once (pads k=85..103 stay zero forever)
  for (int c = tid; c < 3 * 2 * SROWS * 104; c += 256) ((u16*)sX)[c] = 0;

  for (int t = 1; t <= TSTEPS; ++t) {
    // ---- poll h(t-1) flags (wave 0) while waves 1-3 stage x gates ----
    if (wave == 0) {
      if (t > 1) {
        const u32 target = (u32)(t - 1);
        for (;;) {
          u32 a = (lane < NPART) ? ld_u32_llc(&gflag[lane]) : target;
          if (__all(a >= target)) break;
        }
      }
    } else {
      const int g = wave - 1;
      const float* nsrc = (g == 0) ? nr : ((g == 1) ? nz : nh);
      const size_t xoff = ((size_t)(t - 1) * NB + strip * SROWS) * DIN;
      for (int c = lane; c < SROWS * DIN; c += 64) {
        int row = c / DIN, k = c - row * DIN;
        float v = x[xoff + c] + nsrc[xoff + c];
        u16 hi = f2bf(v);
        sX[g][0][row][k] = hi;
        sX[g][1][row][k] = f2bf(v - bf2f(hi));
      }
    }
    __syncthreads();

    // ---- phase C (small-ws inline out-projection): out(t-2) from h(t-1) ----
    if (do_c && t >= 2) {
      const u32* hpl = h_pk + (size_t)((t - 1) & 1) * NB * HID;
      #pragma unroll
      for (int rr = 0; rr < 2; ++rr) {
        const int row = strip * SROWS + part * 2 + rr;
        const int o = tid >> 3, q = tid & 7;
        float a = 0.f;
        #pragma unroll 8
        for (int k2 = 0; k2 < 64; ++k2) {
          u32 v = ld_u32_llc(&hpl[(size_t)row * HID + q * 64 + k2]);
          a += (bf2f((u16)(v >> 16)) + bf2f((u16)(v & 0xFFFFu))) * Wro[(size_t)o * HID + q * 64 + k2];
        }
        __syncthreads();
        sC2[o * 8 + q] = a;
        if (tid < 8) {
          float a2 = 0.f;
          #pragma unroll 8
          for (int k2 = 0; k2 < 64; ++k2) {
            u32 v = ld_u32_llc(&hpl[(size_t)row * HID + tid * 64 + k2]);
            a2 += (bf2f((u16)(v >> 16)) + bf2f((u16)(v & 0xFFFFu))) * Wro[(size_t)32 * HID + tid * 64 + k2];
          }
          sC2[32 * 8 + tid] = a2;
        }
        __syncthreads();
        if (tid < ODIM) {
          float s = bro[tid];
          #pragma unroll
          for (int q2 = 0; q2 < 8; ++q2) s += sC2[tid * 8 + q2];
          out[(size_t)((t - 2) * NB + row) * ODIM + tid] = s;
        }
        __syncthreads();
      }
    }

    // ---- stage h(t-1) strip (one exchange per step): 16 u64/thread agent loads ----
    {
      const u64* hsrc = (const u64*)(h_pk + (size_t)((t - 1) & 1) * NB * HID);
      u64 hreg[SROWS];
      #pragma unroll
      for (int i = 0; i < SROWS; ++i)
        hreg[i] = ld_u64_llc(&hsrc[(size_t)(strip * SROWS + i) * 256 + tid]);
      #pragma unroll
      for (int i = 0; i < SROWS; ++i) {
        u32 v0 = (u32)hreg[i], v1 = (u32)(hreg[i] >> 32);
        *(u32*)&sHh[i][tid * 2] = (v0 >> 16) | (v1 & 0xFFFF0000u);
        *(u32*)&sHl[i][tid * 2] = (v0 & 0xFFFFu) | (v1 << 16);
      }
    }
    __syncthreads();

    // ---- R-full GEMM [16x512] + Z-slice GEMM [16x16/wave] ----
    f32x4 aR[8];
    #pragma unroll
    for (int nf = 0; nf < 8; ++nf) aR[nf] = {0.f, 0.f, 0.f, 0.f};
    f32x4 aZ = {0.f, 0.f, 0.f, 0.f};

    #pragma unroll
    for (int ks = 0; ks < 3; ++ks) {   // x parts (K=96)
      int kk = ks * 32 + 8 * (lane >> 4);
      bf16x8 xRh = bc8(*(const uint4*)&sX[0][0][rowl][kk]);
      bf16x8 xRl = bc8(*(const uint4*)&sX[0][1][rowl][kk]);
      bf16x8 xZh = bc8(*(const uint4*)&sX[1][0][rowl][kk]);
      bf16x8 xZl = bc8(*(const uint4*)&sX[1][1][rowl][kk]);
      bf16x8 wzh = bc8(*(const uint4*)&WXZh[(size_t)colS * DPAD + kk]);
      bf16x8 wzl = bc8(*(const uint4*)&WXZl[(size_t)colS * DPAD + kk]);
      aZ = mfma_bf16(xZh, wzh, aZ);
      aZ = mfma_bf16(xZl, wzh, aZ);
      aZ = mfma_bf16(xZh, wzl, aZ);
      #pragma unroll
      for (int nf = 0; nf < 8; ++nf) {
        bf16x8 wrh = bc8(*(const uint4*)&WXRh[(size_t)colR[nf] * DPAD + kk]);
        bf16x8 wrl = bc8(*(const uint4*)&WXRl[(size_t)colR[nf] * DPAD + kk]);
        aR[nf] = mfma_bf16(xRh, wrh, aR[nf]);
        aR[nf] = mfma_bf16(xRl, wrh, aR[nf]);
        aR[nf] = mfma_bf16(xRh, wrl, aR[nf]);
      }
    }
    #pragma unroll
    for (int ks16 = 0; ks16 < 16; ++ks16) {   // h parts (K=512, split h)
      int k = ks16 * 32 + 8 * (lane >> 4);
      bf16x8 ah = bc8(*(const uint4*)&sHh[rowl][k]);
      bf16x8 al = bc8(*(const uint4*)&sHl[rowl][k]);
      bf16x8 bwz = bc8(*(const uint4*)&WZ[(size_t)colS * HID + k]);
      aZ = mfma_bf16(ah, bwz, aZ);
      aZ = mfma_bf16(al, bwz, aZ);
      #pragma unroll
      for (int nf = 0; nf < 8; ++nf) {
        bf16x8 bw = bc8(*(const uint4*)&WR[(size_t)colR[nf] * HID + k]);
        aR[nf] = mfma_bf16(ah, bw, aR[nf]);
        aR[nf] = mfma_bf16(al, bw, aR[nf]);
      }
    }

    // ---- g = sigmoid(R) * h_precise (reads sH before overwrite); Z values ----
    float Zv[4];
    #pragma unroll
    for (int r = 0; r < 4; ++r) Zv[r] = fsigmoid(aZ[r] + bZv);
    u32 gpk[8][4];
    #pragma unroll
    for (int nf = 0; nf < 8; ++nf)
      #pragma unroll
      for (int r = 0; r < 4; ++r) {
        int row = (lane >> 4) * 4 + r;
        float Rv = fsigmoid(aR[nf][r] + bR[nf]);
        float hp = bf2f(sHh[row][colR[nf]]) + bf2f(sHl[row][colR[nf]]);
        float g = Rv * hp;
        u16 gh = f2bf(g);
        u16 gl = f2bf(g - bf2f(gh));
        gpk[nf][r] = ((u32)gh << 16) | (u32)gl;
      }
    __syncthreads();   // all sH reads done
    #pragma unroll
    for (int nf = 0; nf < 8; ++nf)
      #pragma unroll
      for (int r = 0; r < 4; ++r) {
        int row = (lane >> 4) * 4 + r;
        sGh[row][colR[nf]] = (u16)(gpk[nf][r] >> 16);
        sGl[row][colR[nf]] = (u16)(gpk[nf][r] & 0xFFFFu);
      }
    __syncthreads();   // g planes ready

    // ---- Hhat-slice GEMM [16x16/wave] over split g ----
    f32x4 aH = {0.f, 0.f, 0.f, 0.f};
    #pragma unroll
    for (int ks = 0; ks < 3; ++ks) {
      int kk = ks * 32 + 8 * (lane >> 4);
      bf16x8 xHh = bc8(*(const uint4*)&sX[2][0][rowl][kk]);
      bf16x8 xHl = bc8(*(const uint4*)&sX[2][1][rowl][kk]);
      bf16x8 whh = bc8(*(const uint4*)&WXHh[(size_t)colS * DPAD + kk]);
      bf16x8 whl = bc8(*(const uint4*)&WXHl[(size_t)colS * DPAD + kk]);
      aH = mfma_bf16(xHh, whh, aH);
      aH = mfma_bf16(xHl, whh, aH);
      aH = mfma_bf16(xHh, whl, aH);
    }
    #pragma unroll
    for (int ks16 = 0; ks16 < 16; ++ks16) {
      int k = ks16 * 32 + 8 * (lane >> 4);
      bf16x8 gh8 = bc8(*(const uint4*)&sGh[rowl][k]);
      bf16x8 gl8 = bc8(*(const uint4*)&sGl[rowl][k]);
      bf16x8 bw = bc8(*(const uint4*)&WH[(size_t)colS * HID + k]);
      aH = mfma_bf16(gh8, bw, aH);
      aH = mfma_bf16(gl8, bw, aH);
    }

    // ---- update h, store slice to plane t&1 ----
    u16 hiv[4];
    u32* hdst = h_pk + (size_t)(t & 1) * NB * HID;
    #pragma unroll
    for (int r = 0; r < 4; ++r) {
      int row = (lane >> 4) * 4 + r;
      float Hv = ftanh(aH[r] + bHv);
      float hn = Zv[r] * h_old[r] + (1.0f - Zv[r]) * Hv;
      h_old[r] = hn;
      u16 hi = f2bf(hn);
      u16 lo = f2bf(hn - bf2f(hi));
      hiv[r] = hi;
      st_u32_llc(&hdst[(size_t)(strip * SROWS + row) * HID + colS], ((u32)hi << 16) | (u32)lo);
    }
    __syncthreads();   // drains all waves' stores (vmcnt 0) before flag
    if (tid == 0) st_u32_llc(&gflag[part], (u32)t);

    // hs_out AFTER flag: HBM write latency off the critical path
    if (hs_out) {
      #pragma unroll
      for (int r = 0; r < 4; ++r) {
        int row = (lane >> 4) * 4 + r;
        hs_out[(size_t)((t - 1) * NB + strip * SROWS + row) * HID + colS] = hiv[r];
      }
    }
  }

  // ---- final phase C (small-ws): out(TSTEPS-1) from h(TSTEPS) ----
  if (do_c) {
    if (wave == 0) {
      const u32 target = (u32)TSTEPS;
      for (;;) {
        u32 a = (lane < NPART) ? ld_u32_llc(&gflag[lane]) : target;
        if (__all(a >= target)) break;
      }
    }
    __syncthreads();
    const u32* hpl = h_pk + (size_t)(TSTEPS & 1) * NB * HID;
    #pragma unroll
    for (int rr = 0; rr < 2; ++rr) {
      const int row = strip * SROWS + part * 2 + rr;
      const int o = tid >> 3, q = tid & 7;
      float a = 0.f;
      #pragma unroll 8
      for (int k2 = 0; k2 < 64; ++k2) {
        u32 v = ld_u32_llc(&hpl[(size_t)row * HID + q * 64 + k2]);
        a += (bf2f((u16)(v >> 16)) + bf2f((u16)(v & 0xFFFFu))) * Wro[(size_t)o * HID + q * 64 + k2];
      }
      __syncthreads();
      sC2[o * 8 + q] = a;
      if (tid < 8) {
        float a2 = 0.f;
        #pragma unroll 8
        for (int k2 = 0; k2 < 64; ++k2) {
          u32 v = ld_u32_llc(&hpl[(size_t)row * HID + tid * 64 + k2]);
          a2 += (bf2f((u16)(v >> 16)) + bf2f((u16)(v & 0xFFFFu))) * Wro[(size_t)32 * HID + tid * 64 + k2];
        }
        sC2[32 * 8 + tid] = a2;
      }
      __syncthreads();
      if (tid < ODIM) {
        float s = bro[tid];
        #pragma unroll
        for (int q2 = 0; q2 < 8; ++q2) s += sC2[tid * 8 + q2];
        out[(size_t)((TSTEPS - 1) * NB + row) * ODIM + tid] = s;
      }
      __syncthreads();
    }
  }
}

// ---------------- output projection (big-ws path) ----------------
__global__ void __launch_bounds__(256) out_kernel(
    const u16* __restrict__ hs_out,
    const u16* __restrict__ w_rob, const float* __restrict__ b_ro,
    float* __restrict__ out)
{
  __shared__ __attribute__((aligned(16))) u16 sOh[128][72];

  const int m0   = blockIdx.x * 128;
  const int tid  = threadIdx.x;
  const int lane = tid & 63, wave = tid >> 6;

  f32x4 acc[2][3];
  for (int a = 0; a < 2; ++a) for (int b = 0; b < 3; ++b) acc[a][b] = {0.f, 0.f, 0.f, 0.f};

  for (int kc = 0; kc < 8; ++kc) {
    __syncthreads();
    #pragma unroll
    for (int i = 0; i < 4; ++i) {
      int c = tid + 256 * i; int row = c >> 3, seg = c & 7;
      *(uint4*)&sOh[row][seg * 8] =
        *(const uint4*)&hs_out[(size_t)(m0 + row) * HID + kc * 64 + seg * 8];
    }
    __syncthreads();
    #pragma unroll
    for (int ks = 0; ks < 2; ++ks) {
      int klocal = ks * 32 + 8 * (lane >> 4);
      int kglob  = kc * 64 + klocal;
      bf16x8 ah[2];
      #pragma unroll
      for (int mf = 0; mf < 2; ++mf) {
        int rowl = wave * 32 + mf * 16 + (lane & 15);
        ah[mf] = bc8(*(const uint4*)&sOh[rowl][klocal]);
      }
      #pragma unroll
      for (int nf = 0; nf < 3; ++nf) {
        int wrow = nf * 16 + (lane & 15);
        bf16x8 bw = bc8(*(const uint4*)&w_rob[(size_t)wrow * HID + kglob]);
        #pragma unroll
        for (int mf = 0; mf < 2; ++mf)
          acc[mf][nf] = mfma_bf16(ah[mf], bw, acc[mf][nf]);
      }
    }
  }
  for (int nf = 0; nf < 3; ++nf) {
    int o = nf * 16 + (lane & 15);
    if (o < ODIM) {
      float bb = b_ro[o];
      for (int mf = 0; mf < 2; ++mf)
        for (int r = 0; r < 4; ++r) {
          int R = m0 + wave * 32 + mf * 16 + (lane >> 4) * 4 + r;
          out[(size_t)R * ODIM + o] = acc[mf][nf][r] + bb;
        }
    }
  }
}

// ---------------- launcher ----------------
extern "C" void kernel_launch(void* const* d_in, const int* in_sizes, int n_in,
                              void* d_out, int out_size, void* d_ws, size_t ws_size,
                              hipStream_t stream)
{
  const float* x   = (const float*)d_in[0];
  const float* nr  = (const float*)d_in[1];
  const float* nz  = (const float*)d_in[2];
  const float* nh  = (const float*)d_in[3];
  const float* Wxr = (const float*)d_in[4];
  const float* Wxz = (const float*)d_in[5];
  const float* Wxh = (const float*)d_in[6];
  const float* Whr = (const float*)d_in[7];
  const float* bhr = (const float*)d_in[8];
  const float* Whz = (const float*)d_in[9];
  const float* bhz = (const float*)d_in[10];
  const float* Whh = (const float*)d_in[11];
  const float* bhh = (const float*)d_in[12];
  const float* Wro = (const float*)d_in[13];
  const float* bro = (const float*)d_in[14];
  float* out = (float*)d_out;

  char* ws = (char*)d_ws;
  size_t off = 0;
  auto alloc = [&](size_t bytes) -> char* {
    char* p = ws + off;
    off += (bytes + 255) & ~(size_t)255;
    return p;
  };
  u32*  h_pk  = (u32*) alloc((size_t)2 * NB * HID * 4);   // packed hi|lo h, double-buffered
  u16*  w_hb  = (u16*) alloc((size_t)3 * HID * HID * 2);
  u16*  wx_hi = (u16*) alloc((size_t)3 * HID * DPAD * 2);
  u16*  wx_lo = (u16*) alloc((size_t)3 * HID * DPAD * 2);
  u16*  w_rob = (u16*) alloc((size_t)OPAD * HID * 2);
  u32*  flags = (u32*) alloc((size_t)16 * 16 * 4);        // 16 strips x one 64B line
  size_t small_need = off;
  if (ws_size < small_need) return;   // fail numerically, never scribble

  u16* hs_out = (u16*)(ws + off);
  size_t big_need = off + (size_t)TBROWS * HID * 2 + 256;
  bool big = (ws_size >= big_need);
  if (!big) hs_out = nullptr;

  hipMemsetAsync(flags, 0, (size_t)16 * 16 * 4, stream);
  hipMemsetAsync(h_pk,  0, (size_t)NB * HID * 4, stream);   // plane 0 = h(0) = 0

  prep_kernel<<<512, 256, 0, stream>>>(Whr, Whz, Whh, Wxr, Wxz, Wxh, Wro,
                                       w_hb, wx_hi, wx_lo, w_rob);

  recur_kernel<<<NBLK, 256, 0, stream>>>(
      x, nr, nz, nh, bhr, bhz, bhh, wx_hi, wx_lo, w_hb,
      h_pk, flags, hs_out, Wro, bro, out, big ? 0 : 1);

  if (big)
    out_kernel<<<TBROWS / 128, 256, 0, stream>>>(hs_out, w_rob, bro, out);
}

// Round 9
// 7822.095 us; speedup vs baseline: 2.7563x; 2.7563x over previous
//
#include <hip/hip_runtime.h>
#include <stdint.h>

// ---------------- problem constants ----------------
#define TSTEPS 512
#define NB     256
#define DIN    85
#define DPAD   96
#define HID    512
#define ODIM   33
#define OPAD   48
#define TBROWS (TSTEPS*NB)
#define NBLK   256          // 16 strips x 16 parts
#define SROWS  16
#define NPART  16

typedef unsigned int u32;
typedef unsigned short u16;
typedef unsigned long long u64;
typedef __bf16 bf16x8 __attribute__((ext_vector_type(8)));
typedef float  f32x4  __attribute__((ext_vector_type(4)));

__device__ __forceinline__ u16 f2bf(float f) {
  u32 u = __float_as_uint(f);
  return (u16)((u + 0x7FFFu + ((u >> 16) & 1u)) >> 16);   // RNE
}
__device__ __forceinline__ float bf2f(u16 h) {
  return __uint_as_float(((u32)h) << 16);
}
__device__ __forceinline__ bf16x8 bc8(uint4 v) { return __builtin_bit_cast(bf16x8, v); }
__device__ __forceinline__ f32x4 mfma_bf16(bf16x8 a, bf16x8 b, f32x4 c) {
  return __builtin_amdgcn_mfma_f32_16x16x32_bf16(a, b, c, 0, 0, 0);
}
__device__ __forceinline__ float fsigmoid(float x) { return 1.0f / (1.0f + __expf(-x)); }
__device__ __forceinline__ float ftanh(float x)    { return 2.0f / (1.0f + __expf(-2.0f*x)) - 1.0f; }

// agent-scope (LLC-coherent) relaxed ops for cross-block mutable data
__device__ __forceinline__ void st_u32_llc(u32* p, u32 v) {
  __hip_atomic_store(p, v, __ATOMIC_RELAXED, __HIP_MEMORY_SCOPE_AGENT);
}
__device__ __forceinline__ void st_u64_llc(u64* p, u64 v) {
  __hip_atomic_store(p, v, __ATOMIC_RELAXED, __HIP_MEMORY_SCOPE_AGENT);
}
__device__ __forceinline__ u32 ld_u32_llc(const u32* p) {
  return __hip_atomic_load(p, __ATOMIC_RELAXED, __HIP_MEMORY_SCOPE_AGENT);
}
__device__ __forceinline__ u64 ld_u64_llc(const u64* p) {
  return __hip_atomic_load(p, __ATOMIC_RELAXED, __HIP_MEMORY_SCOPE_AGENT);
}
// prevent hoisting of data loads above a completed poll (rule #18 analog)
#define POLL_FENCE() do { asm volatile("" ::: "memory"); __builtin_amdgcn_sched_barrier(0); } while (0)

// pack 8 tagged u32 (hi16|lo16 per element) into hi / lo bf16x8 fragments
__device__ __forceinline__ bf16x8 frag_hi(const u32 u[8]) {
  uint4 w;
  w.x = (u[0] >> 16) | (u[1] & 0xFFFF0000u);
  w.y = (u[2] >> 16) | (u[3] & 0xFFFF0000u);
  w.z = (u[4] >> 16) | (u[5] & 0xFFFF0000u);
  w.w = (u[6] >> 16) | (u[7] & 0xFFFF0000u);
  return bc8(w);
}
__device__ __forceinline__ bf16x8 frag_lo(const u32 u[8]) {
  uint4 w;
  w.x = (u[0] & 0xFFFFu) | (u[1] << 16);
  w.y = (u[2] & 0xFFFFu) | (u[3] << 16);
  w.z = (u[4] & 0xFFFFu) | (u[5] << 16);
  w.w = (u[6] & 0xFFFFu) | (u[7] << 16);
  return bc8(w);
}

// ---------------- prep: bf16 weight conversions ----------------
__global__ void __launch_bounds__(256) prep_kernel(
    const float* __restrict__ Whr, const float* __restrict__ Whz, const float* __restrict__ Whh,
    const float* __restrict__ Wxr, const float* __restrict__ Wxz, const float* __restrict__ Wxh,
    const float* __restrict__ Wro,
    u16* __restrict__ w_hb, u16* __restrict__ wx_hi, u16* __restrict__ wx_lo,
    u16* __restrict__ w_rob)
{
  int tid = blockIdx.x * blockDim.x + threadIdx.x;
  int np  = gridDim.x * blockDim.x;
  for (int i = tid; i < 3 * HID * HID; i += np) {
    int m = i / (HID * HID), r = i % (HID * HID);
    const float* src = (m == 0) ? Whr : ((m == 1) ? Whz : Whh);
    w_hb[i] = f2bf(src[r]);
  }
  for (int i = tid; i < 3 * HID * DPAD; i += np) {
    int m = i / (HID * DPAD), r = i % (HID * DPAD);
    int row = r / DPAD, k = r % DPAD;
    const float* src = (m == 0) ? Wxr : ((m == 1) ? Wxz : Wxh);
    u16 hi = 0, lo = 0;
    if (k < DIN) {
      float v = src[row * DIN + k];
      hi = f2bf(v);
      lo = f2bf(v - bf2f(hi));
    }
    wx_hi[i] = hi; wx_lo[i] = lo;
  }
  for (int i = tid; i < OPAD * HID; i += np) {
    int row = i / HID, k = i % HID;
    w_rob[i] = (row < ODIM) ? f2bf(Wro[row * HID + k]) : (u16)0;
  }
}

// ---------------- persistent recurrence kernel ----------------
// h / g stored TRANSPOSED per strip: u32 index = (strip*512 + col)*16 + row(0..15)
__global__ void __launch_bounds__(256, 1) recur_kernel(
    const float* __restrict__ x,  const float* __restrict__ nr,
    const float* __restrict__ nz, const float* __restrict__ nh,
    const float* __restrict__ bhr, const float* __restrict__ bhz, const float* __restrict__ bhh,
    const u16* __restrict__ wx_hi, const u16* __restrict__ wx_lo, const u16* __restrict__ w_hb,
    u32* __restrict__ h_pk, u32* __restrict__ g_pk, u32* __restrict__ flags,
    u16* __restrict__ hs_out,
    const float* __restrict__ Wro, const float* __restrict__ bro, float* __restrict__ out,
    int do_c)
{
  __shared__ __attribute__((aligned(16))) u16 sX[3][2][SROWS][104];   // 19968 B
  __shared__ __attribute__((aligned(16))) float sC[2][2][64][4];      // 4096 B (combine + C scratch)

  const int tid  = threadIdx.x;
  const int lane = tid & 63;
  const int wave = tid >> 6;
  const int strip = (int)blockIdx.x >> 4;    // 0..15 (16 batch rows each)
  const int part  = (int)blockIdx.x & 15;    // 0..15 (32 cols each)
  const int kh = wave >> 1;                  // k-half
  const int ct = wave & 1;                   // col-tile (16 cols)
  const int rowl  = lane & 15;
  const int rquad = lane >> 4;               // 0..3
  const int scol  = part * 32 + ct * 16 + rowl;   // this lane's output column

  u32* flagA = flags + strip * 32;           // g-ready, one 64B line
  u32* flagB = flags + strip * 32 + 16;      // h-ready, next 64B line

  const u16* WR = w_hb;
  const u16* WZ = w_hb + (size_t)HID * HID;
  const u16* WH = w_hb + (size_t)2 * HID * HID;
  const u16* WXRh = wx_hi;                          const u16* WXRl = wx_lo;
  const u16* WXZh = wx_hi + (size_t)HID * DPAD;     const u16* WXZl = wx_lo + (size_t)HID * DPAD;
  const u16* WXHh = wx_hi + (size_t)2 * HID * DPAD; const u16* WXHl = wx_lo + (size_t)2 * HID * DPAD;

  const float bRv = bhr[scol], bZv = bhz[scol], bHv = bhh[scol];

  float h_old[4] = {0.f, 0.f, 0.f, 0.f};
  float zv[4]    = {0.f, 0.f, 0.f, 0.f};

  // zero x k-pads once (cols 85..103, both planes, 3 gates)
  for (int c = tid; c < 3 * 2 * SROWS * (104 - DIN); c += 256) {
    int g = c / (2 * SROWS * 19), r1 = c % (2 * SROWS * 19);
    int pl = r1 / (SROWS * 19),   r2 = r1 % (SROWS * 19);
    int row = r2 / 19, k = DIN + r2 % 19;
    sX[g][pl][row][k] = 0;
  }
  // stage x(1)
  {
    const size_t xbase = (size_t)(strip * SROWS) * DIN;
    for (int c = tid; c < 3 * SROWS * DIN; c += 256) {
      int g = c / (SROWS * DIN), rem = c - g * (SROWS * DIN);
      int row = rem / DIN, k = rem - row * DIN;
      const float* nsrc = (g == 0) ? nr : ((g == 1) ? nz : nh);
      float v = x[xbase + rem] + nsrc[xbase + rem];
      u16 hi = f2bf(v);
      sX[g][0][row][k] = hi;
      sX[g][1][row][k] = f2bf(v - bf2f(hi));
    }
  }
  __syncthreads();

  for (int t = 1; t <= TSTEPS; ++t) {
    // ---- poll h(t-1) (all waves) ----
    {
      const u32 target = (u32)(t - 1);
      for (;;) {
        u32 a = (lane < NPART) ? ld_u32_llc(&flagB[lane]) : target;
        if (__all(a >= target)) break;
      }
      POLL_FENCE();
    }
    const u32* Hb = h_pk + (size_t)((t - 1) & 1) * NB * HID + (size_t)strip * 512 * 16;

    // ---- phase C (small-ws): out(t-2) from h(t-1), batch row strip*16+part ----
    if (do_c && t >= 2) {
      float* scz = (float*)sC;
      const int o = tid >> 3, q = tid & 7;
      float a = 0.f;
      #pragma unroll 8
      for (int k2 = 0; k2 < 64; ++k2) {
        u32 v = ld_u32_llc(&Hb[(q * 64 + k2) * 16 + part]);
        a += (bf2f((u16)(v >> 16)) + bf2f((u16)(v & 0xFFFFu))) * Wro[(size_t)o * HID + q * 64 + k2];
      }
      __syncthreads();
      scz[o * 8 + q] = a;
      if (tid < 8) {
        float a2 = 0.f;
        #pragma unroll 8
        for (int k2 = 0; k2 < 64; ++k2) {
          u32 v = ld_u32_llc(&Hb[(tid * 64 + k2) * 16 + part]);
          a2 += (bf2f((u16)(v >> 16)) + bf2f((u16)(v & 0xFFFFu))) * Wro[(size_t)32 * HID + tid * 64 + k2];
        }
        scz[32 * 8 + tid] = a2;
      }
      __syncthreads();
      if (tid < ODIM) {
        float s = bro[tid];
        #pragma unroll
        for (int q2 = 0; q2 < 8; ++q2) s += scz[tid * 8 + q2];
        out[(size_t)((t - 2) * NB + strip * SROWS + part) * ODIM + tid] = s;
      }
      __syncthreads();
    }

    // ---- preload precise h for the g-product (kh==0 waves) ----
    u64 hp2[2] = {0, 0};
    if (kh == 0) {
      const u64* hb64 = (const u64*)Hb;
      int bi = scol * 8 + rquad * 2;
      hp2[0] = ld_u64_llc(&hb64[bi]);
      hp2[1] = ld_u64_llc(&hb64[bi + 1]);
    }

    // ================= PHASE A: R and Z (k-split wave pairs) =================
    f32x4 aR = {0.f, 0.f, 0.f, 0.f}, aZ = {0.f, 0.f, 0.f, 0.f};
    if (kh == 0) {   // x-projections (K=96) on the k-lower waves
      #pragma unroll
      for (int ks = 0; ks < 3; ++ks) {
        int kk = ks * 32 + rquad * 8;
        bf16x8 xrh = bc8(*(const uint4*)&sX[0][0][rowl][kk]);
        bf16x8 xrl = bc8(*(const uint4*)&sX[0][1][rowl][kk]);
        bf16x8 xzh = bc8(*(const uint4*)&sX[1][0][rowl][kk]);
        bf16x8 xzl = bc8(*(const uint4*)&sX[1][1][rowl][kk]);
        bf16x8 wrh = bc8(*(const uint4*)&WXRh[(size_t)scol * DPAD + kk]);
        bf16x8 wrl = bc8(*(const uint4*)&WXRl[(size_t)scol * DPAD + kk]);
        bf16x8 wzh = bc8(*(const uint4*)&WXZh[(size_t)scol * DPAD + kk]);
        bf16x8 wzl = bc8(*(const uint4*)&WXZl[(size_t)scol * DPAD + kk]);
        aR = mfma_bf16(xrh, wrh, aR); aR = mfma_bf16(xrl, wrh, aR); aR = mfma_bf16(xrh, wrl, aR);
        aZ = mfma_bf16(xzh, wzh, aZ); aZ = mfma_bf16(xzl, wzh, aZ); aZ = mfma_bf16(xzh, wzl, aZ);
      }
    }
    #pragma unroll
    for (int c = 0; c < 8; ++c) {
      int cc = kh * 8 + c;
      u32 u[8];
      #pragma unroll
      for (int j = 0; j < 8; ++j)
        u[j] = ld_u32_llc(&Hb[(cc * 32 + rquad * 8 + j) * 16 + rowl]);
      bf16x8 ah = frag_hi(u), al = frag_lo(u);
      bf16x8 bwR = bc8(*(const uint4*)&WR[(size_t)scol * HID + cc * 32 + rquad * 8]);
      bf16x8 bwZ = bc8(*(const uint4*)&WZ[(size_t)scol * HID + cc * 32 + rquad * 8]);
      aR = mfma_bf16(ah, bwR, aR); aR = mfma_bf16(al, bwR, aR);
      aZ = mfma_bf16(ah, bwZ, aZ); aZ = mfma_bf16(al, bwZ, aZ);
    }
    if (kh == 1) {
      *(f32x4*)&sC[0][ct][lane][0] = aR;
      *(f32x4*)&sC[1][ct][lane][0] = aZ;
    }
    __syncthreads();
    if (kh == 0) {
      f32x4 oR = *(const f32x4*)&sC[0][ct][lane][0];
      f32x4 oZ = *(const f32x4*)&sC[1][ct][lane][0];
      u32 gp[4];
      #pragma unroll
      for (int r = 0; r < 4; ++r) {
        float Rv = fsigmoid(aR[r] + oR[r] + bRv);
        zv[r]    = fsigmoid(aZ[r] + oZ[r] + bZv);
        u32 hpu = (u32)(hp2[r >> 1] >> ((r & 1) * 32));
        float hprec = bf2f((u16)(hpu >> 16)) + bf2f((u16)(hpu & 0xFFFFu));
        float g = Rv * hprec;
        u16 gh = f2bf(g);
        u16 gl = f2bf(g - bf2f(gh));
        gp[r] = ((u32)gh << 16) | (u32)gl;
      }
      u64* gb64 = (u64*)(g_pk + (size_t)strip * 512 * 16);
      int bi = scol * 8 + rquad * 2;
      st_u64_llc(&gb64[bi],     (u64)gp[0] | ((u64)gp[1] << 32));
      st_u64_llc(&gb64[bi + 1], (u64)gp[2] | ((u64)gp[3] << 32));
    }
    __syncthreads();   // drain all stores (vmcnt 0) before flag
    if (tid == 0) st_u32_llc(&flagA[part], (u32)t);

    // ---- poll g(t) (all waves) ----
    {
      const u32 target = (u32)t;
      for (;;) {
        u32 a = (lane < NPART) ? ld_u32_llc(&flagA[lane]) : target;
        if (__all(a >= target)) break;
      }
      POLL_FENCE();
    }
    const u32* Gb = g_pk + (size_t)strip * 512 * 16;

    // ================= PHASE B: Hhat (k-split) + state update =================
    f32x4 aH = {0.f, 0.f, 0.f, 0.f};
    if (kh == 0) {
      #pragma unroll
      for (int ks = 0; ks < 3; ++ks) {
        int kk = ks * 32 + rquad * 8;
        bf16x8 xhh = bc8(*(const uint4*)&sX[2][0][rowl][kk]);
        bf16x8 xhl = bc8(*(const uint4*)&sX[2][1][rowl][kk]);
        bf16x8 whh = bc8(*(const uint4*)&WXHh[(size_t)scol * DPAD + kk]);
        bf16x8 whl = bc8(*(const uint4*)&WXHl[(size_t)scol * DPAD + kk]);
        aH = mfma_bf16(xhh, whh, aH);
        aH = mfma_bf16(xhl, whh, aH);
        aH = mfma_bf16(xhh, whl, aH);
      }
    }
    #pragma unroll
    for (int c = 0; c < 8; ++c) {
      int cc = kh * 8 + c;
      u32 u[8];
      #pragma unroll
      for (int j = 0; j < 8; ++j)
        u[j] = ld_u32_llc(&Gb[(cc * 32 + rquad * 8 + j) * 16 + rowl]);
      bf16x8 gh8 = frag_hi(u), gl8 = frag_lo(u);
      bf16x8 bwH = bc8(*(const uint4*)&WH[(size_t)scol * HID + cc * 32 + rquad * 8]);
      aH = mfma_bf16(gh8, bwH, aH);
      aH = mfma_bf16(gl8, bwH, aH);
    }
    if (kh == 1) *(f32x4*)&sC[0][ct][lane][0] = aH;
    __syncthreads();

    u16 hiv[4];
    if (kh == 0) {
      f32x4 oH = *(const f32x4*)&sC[0][ct][lane][0];
      u32 hp[4];
      #pragma unroll
      for (int r = 0; r < 4; ++r) {
        float Hv = ftanh(aH[r] + oH[r] + bHv);
        float hn = zv[r] * h_old[r] + (1.0f - zv[r]) * Hv;
        h_old[r] = hn;
        u16 hi = f2bf(hn);
        u16 lo = f2bf(hn - bf2f(hi));
        hp[r] = ((u32)hi << 16) | (u32)lo;
        hiv[r] = hi;
      }
      u64* hb64w = (u64*)(h_pk + (size_t)(t & 1) * NB * HID + (size_t)strip * 512 * 16);
      int bi = scol * 8 + rquad * 2;
      st_u64_llc(&hb64w[bi],     (u64)hp[0] | ((u64)hp[1] << 32));
      st_u64_llc(&hb64w[bi + 1], (u64)hp[2] | ((u64)hp[3] << 32));
    }
    __syncthreads();   // drain
    if (tid == 0) st_u32_llc(&flagB[part], (u32)t);

    // off critical path: hs_out + stage x(t+1)
    if (hs_out && kh == 0) {
      #pragma unroll
      for (int r = 0; r < 4; ++r)
        hs_out[(size_t)((t - 1) * NB + strip * SROWS + rquad * 4 + r) * HID + scol] = hiv[r];
    }
    if (t < TSTEPS) {
      const size_t xbase = ((size_t)t * NB + strip * SROWS) * DIN;
      for (int c = tid; c < 3 * SROWS * DIN; c += 256) {
        int g = c / (SROWS * DIN), rem = c - g * (SROWS * DIN);
        int row = rem / DIN, k = rem - row * DIN;
        const float* nsrc = (g == 0) ? nr : ((g == 1) ? nz : nh);
        float v = x[xbase + rem] + nsrc[xbase + rem];
        u16 hi = f2bf(v);
        sX[g][0][row][k] = hi;
        sX[g][1][row][k] = f2bf(v - bf2f(hi));
      }
    }
    __syncthreads();
  }

  // ---- final phase C (small-ws): out(TSTEPS-1) from h(TSTEPS) ----
  if (do_c) {
    {
      const u32 target = (u32)TSTEPS;
      for (;;) {
        u32 a = (lane < NPART) ? ld_u32_llc(&flagB[lane]) : target;
        if (__all(a >= target)) break;
      }
      POLL_FENCE();
    }
    const u32* Hb = h_pk + (size_t)(TSTEPS & 1) * NB * HID + (size_t)strip * 512 * 16;
    float* scz = (float*)sC;
    const int o = tid >> 3, q = tid & 7;
    float a = 0.f;
    #pragma unroll 8
    for (int k2 = 0; k2 < 64; ++k2) {
      u32 v = ld_u32_llc(&Hb[(q * 64 + k2) * 16 + part]);
      a += (bf2f((u16)(v >> 16)) + bf2f((u16)(v & 0xFFFFu))) * Wro[(size_t)o * HID + q * 64 + k2];
    }
    __syncthreads();
    scz[o * 8 + q] = a;
    if (tid < 8) {
      float a2 = 0.f;
      #pragma unroll 8
      for (int k2 = 0; k2 < 64; ++k2) {
        u32 v = ld_u32_llc(&Hb[(tid * 64 + k2) * 16 + part]);
        a2 += (bf2f((u16)(v >> 16)) + bf2f((u16)(v & 0xFFFFu))) * Wro[(size_t)32 * HID + tid * 64 + k2];
      }
      scz[32 * 8 + tid] = a2;
    }
    __syncthreads();
    if (tid < ODIM) {
      float s = bro[tid];
      #pragma unroll
      for (int q2 = 0; q2 < 8; ++q2) s += scz[tid * 8 + q2];
      out[(size_t)((TSTEPS - 1) * NB + strip * SROWS + part) * ODIM + tid] = s;
    }
  }
}

// ---------------- output projection (big-ws path) ----------------
__global__ void __launch_bounds__(256) out_kernel(
    const u16* __restrict__ hs_out,
    const u16* __restrict__ w_rob, const float* __restrict__ b_ro,
    float* __restrict__ out)
{
  __shared__ __attribute__((aligned(16))) u16 sOh[128][72];

  const int m0   = blockIdx.x * 128;
  const int tid  = threadIdx.x;
  const int lane = tid & 63, wave = tid >> 6;

  f32x4 acc[2][3];
  for (int a = 0; a < 2; ++a) for (int b = 0; b < 3; ++b) acc[a][b] = {0.f, 0.f, 0.f, 0.f};

  for (int kc = 0; kc < 8; ++kc) {
    __syncthreads();
    #pragma unroll
    for (int i = 0; i < 4; ++i) {
      int c = tid + 256 * i; int row = c >> 3, seg = c & 7;
      *(uint4*)&sOh[row][seg * 8] =
        *(const uint4*)&hs_out[(size_t)(m0 + row) * HID + kc * 64 + seg * 8];
    }
    __syncthreads();
    #pragma unroll
    for (int ks = 0; ks < 2; ++ks) {
      int klocal = ks * 32 + 8 * (lane >> 4);
      int kglob  = kc * 64 + klocal;
      bf16x8 ah[2];
      #pragma unroll
      for (int mf = 0; mf < 2; ++mf) {
        int rowl = wave * 32 + mf * 16 + (lane & 15);
        ah[mf] = bc8(*(const uint4*)&sOh[rowl][klocal]);
      }
      #pragma unroll
      for (int nf = 0; nf < 3; ++nf) {
        int wrow = nf * 16 + (lane & 15);
        bf16x8 bw = bc8(*(const uint4*)&w_rob[(size_t)wrow * HID + kglob]);
        #pragma unroll
        for (int mf = 0; mf < 2; ++mf)
          acc[mf][nf] = mfma_bf16(ah[mf], bw, acc[mf][nf]);
      }
    }
  }
  for (int nf = 0; nf < 3; ++nf) {
    int o = nf * 16 + (lane & 15);
    if (o < ODIM) {
      float bb = b_ro[o];
      for (int mf = 0; mf < 2; ++mf)
        for (int r = 0; r < 4; ++r) {
          int R = m0 + wave * 32 + mf * 16 + (lane >> 4) * 4 + r;
          out[(size_t)R * ODIM + o] = acc[mf][nf][r] + bb;
        }
    }
  }
}

// ---------------- launcher ----------------
extern "C" void kernel_launch(void* const* d_in, const int* in_sizes, int n_in,
                              void* d_out, int out_size, void* d_ws, size_t ws_size,
                              hipStream_t stream)
{
  const float* x   = (const float*)d_in[0];
  const float* nr  = (const float*)d_in[1];
  const float* nz  = (const float*)d_in[2];
  const float* nh  = (const float*)d_in[3];
  const float* Wxr = (const float*)d_in[4];
  const float* Wxz = (const float*)d_in[5];
  const float* Wxh = (const float*)d_in[6];
  const float* Whr = (const float*)d_in[7];
  const float* bhr = (const float*)d_in[8];
  const float* Whz = (const float*)d_in[9];
  const float* bhz = (const float*)d_in[10];
  const float* Whh = (const float*)d_in[11];
  const float* bhh = (const float*)d_in[12];
  const float* Wro = (const float*)d_in[13];
  const float* bro = (const float*)d_in[14];
  float* out = (float*)d_out;

  char* ws = (char*)d_ws;
  size_t off = 0;
  auto alloc = [&](size_t bytes) -> char* {
    char* p = ws + off;
    off += (bytes + 255) & ~(size_t)255;
    return p;
  };
  u32*  h_pk  = (u32*) alloc((size_t)2 * NB * HID * 4);   // transposed [plane][strip][col][row]
  u32*  g_pk  = (u32*) alloc((size_t)NB * HID * 4);       // transposed [strip][col][row]
  u16*  w_hb  = (u16*) alloc((size_t)3 * HID * HID * 2);
  u16*  wx_hi = (u16*) alloc((size_t)3 * HID * DPAD * 2);
  u16*  wx_lo = (u16*) alloc((size_t)3 * HID * DPAD * 2);
  u16*  w_rob = (u16*) alloc((size_t)OPAD * HID * 2);
  u32*  flags = (u32*) alloc((size_t)16 * 32 * 4);        // 16 strips x 2 lines (A,B)
  size_t small_need = off;
  if (ws_size < small_need) return;   // fail numerically, never scribble

  u16* hs_out = (u16*)(ws + off);
  size_t big_need = off + (size_t)TBROWS * HID * 2 + 256;
  bool big = (ws_size >= big_need);
  if (!big) hs_out = nullptr;

  hipMemsetAsync(flags, 0, (size_t)16 * 32 * 4, stream);
  hipMemsetAsync(h_pk,  0, (size_t)NB * HID * 4, stream);   // plane 0 = h(0) = 0

  prep_kernel<<<512, 256, 0, stream>>>(Whr, Whz, Whh, Wxr, Wxz, Wxh, Wro,
                                       w_hb, wx_hi, wx_lo, w_rob);

  recur_kernel<<<NBLK, 256, 0, stream>>>(
      x, nr, nz, nh, bhr, bhz, bhh, wx_hi, wx_lo, w_hb,
      h_pk, g_pk, flags, hs_out, Wro, bro, out, big ? 0 : 1);

  if (big)
    out_kernel<<<TBROWS / 128, 256, 0, stream>>>(hs_out, w_rob, bro, out);
}